// Round 8
// baseline (228.518 us; speedup 1.0000x reference)
//
#include <hip/hip_runtime.h>
#include <hip/hip_bf16.h>
#include <math.h>

#define D_MODEL 1024
#define NHEADS  16
#define DK      64
#define SEQ     2048
#define BATCH   2
#define MROWS   4096   // BATCH*SEQ
#define NQT     (SEQ/64)   // 32 q-tiles

typedef unsigned short ushort_t;
using short8 = __attribute__((ext_vector_type(8))) short;
using f32x4  = __attribute__((ext_vector_type(4))) float;

__device__ __forceinline__ ushort_t f2bf(float x) {
    unsigned u = __float_as_uint(x);
    u = (u + 0x7FFFu + ((u >> 16) & 1u)) >> 16;   // RNE
    return (ushort_t)u;
}

// pack 2 floats -> 2 bf16 in one uint (v_cvt_pk_bf16_f32 on gfx950)
__device__ __forceinline__ unsigned pk2(float a, float b) {
    __hip_bfloat162 h = __float22bfloat162_rn(float2{a, b});
    unsigned u;
    __builtin_memcpy(&u, &h, 4);
    return u;
}

// async global->LDS, 16B per lane; LDS dest = wave-uniform base + lane*16
__device__ __forceinline__ void gll16(const ushort_t* g, ushort_t* l) {
    __builtin_amdgcn_global_load_lds(
        (const __attribute__((address_space(1))) void*)(g),
        (__attribute__((address_space(3))) void*)(l), 16, 0, 0);
}

// ---------------------------------------------------------------------------
// fp32 -> bf16 conversion, 7 tensors in one launch (blockIdx.y selects).
// ---------------------------------------------------------------------------
__global__ __launch_bounds__(256) void cvt_bf16(
    const float* s0, const float* s1, const float* s2, const float* s3,
    const float* s4, const float* s5, const float* s6,
    ushort_t* d0, ushort_t* d1, ushort_t* d2, ushort_t* d3,
    ushort_t* d4, ushort_t* d5, ushort_t* d6, int nIn, int nW)
{
    const float* s; ushort_t* d; int n;
    switch (blockIdx.y) {
        case 0: s = s0; d = d0; n = nIn; break;
        case 1: s = s1; d = d1; n = nIn; break;
        case 2: s = s2; d = d2; n = nIn; break;
        case 3: s = s3; d = d3; n = nW;  break;
        case 4: s = s4; d = d4; n = nW;  break;
        case 5: s = s5; d = d5; n = nW;  break;
        default: s = s6; d = d6; n = nW; break;
    }
    int i = (blockIdx.x * 256 + threadIdx.x) * 4;
    if (i < n) {
        float4 v = *(const float4*)&s[i];
        ushort4 o;
        o.x = f2bf(v.x); o.y = f2bf(v.y); o.z = f2bf(v.z); o.w = f2bf(v.w);
        *(ushort4*)&d[i] = o;
    }
}

// ---------------------------------------------------------------------------
// bf16 MFMA GEMM:  C[M,N] = (A[M,K] @ W[N,K]^T + bias) * oscale
// 128x128 tile, BK=64, 256 threads (4 waves), DOUBLE-BUFFERED global_load_lds
// pipeline (r7 flash pattern): vmcnt(0) waits on loads issued one iteration
// ago; raw s_barrier avoids __syncthreads' full drain; prefetch overlaps
// the MFMA inner loop. LDS 64KB -> 2 blocks/CU.
// MODE 0: bf16 row-major out.  MODE 1: bf16 transposed out [B*H][DK][SEQ].
// MODE 2: fp32 row-major out.
// ---------------------------------------------------------------------------
struct GemmArgs { const ushort_t* A; const ushort_t* W; const float* bias;
                  void* C; int mode; float oscale; };

template<int MODE>
__device__ __forceinline__ void gemm_core(const GemmArgs& ga,
                                          ushort_t* As0, ushort_t* Bs0,
                                          ushort_t* As1, ushort_t* Bs1)
{
    constexpr bool SWP = (MODE != 1);
    const int tid  = threadIdx.x;
    const int w    = tid >> 6, lane = tid & 63;
    const int quad = lane >> 4, lx = lane & 15;
    const int mw = (w >> 1) * 64, nw = (w & 1) * 64;
    const int bm = blockIdx.x * 128, bn = blockIdx.y * 128;
    const int K = D_MODEL;

    // staging: 8 gll16 per wave = As(16KB)+Bs(16KB) per block
    auto stage = [&](int k0, ushort_t* As, ushort_t* Bs) {
#pragma unroll
        for (int i = 0; i < 4; ++i) {
            int r0 = (w * 4 + i) * 8;
            int rl = r0 + (lane >> 3);
            int g  = (lane & 7) ^ (rl & 7);
            gll16(&ga.A[(size_t)(bm + rl) * K + k0 + g * 8], &As[r0 * 64]);
            gll16(&ga.W[(size_t)(bn + rl) * K + k0 + g * 8], &Bs[r0 * 64]);
        }
    };

    f32x4 acc[4][4];
#pragma unroll
    for (int mt = 0; mt < 4; ++mt)
#pragma unroll
        for (int nt = 0; nt < 4; ++nt)
            acc[mt][nt] = (f32x4){0.f, 0.f, 0.f, 0.f};

    float4 b4[4];
    float  bfr[4];
#pragma unroll
    for (int nt = 0; nt < 4; ++nt) {
        if (SWP) b4[nt] = *(const float4*)&ga.bias[bn + nw + nt * 16 + quad * 4];
        else     bfr[nt] = ga.bias[bn + nw + nt * 16 + lx];
    }

    // prologue: stage k-tile 0 into buffer 0
    stage(0, As0, Bs0);

    for (int it = 0; it < K / 64; ++it) {
        ushort_t* As = (it & 1) ? As1 : As0;
        ushort_t* Bs = (it & 1) ? Bs1 : Bs0;

        // tile-it loads were issued one full iteration ago
        asm volatile("s_waitcnt vmcnt(0)" ::: "memory");
        asm volatile("s_barrier" ::: "memory");

        // prefetch next k-tile into the other buffer (overlaps MFMA below)
        if (it + 1 < K / 64)
            stage((it + 1) * 64, (it & 1) ? As0 : As1, (it & 1) ? Bs0 : Bs1);

#pragma unroll
        for (int ks = 0; ks < 2; ++ks) {
            short8 af[4], bf[4];
#pragma unroll
            for (int mt = 0; mt < 4; ++mt) {
                int r = mw + mt * 16 + lx;
                af[mt] = *(const short8*)&As[r * 64 + (((ks * 4 + quad) ^ (r & 7)) << 3)];
            }
#pragma unroll
            for (int nt = 0; nt < 4; ++nt) {
                int r = nw + nt * 16 + lx;
                bf[nt] = *(const short8*)&Bs[r * 64 + (((ks * 4 + quad) ^ (r & 7)) << 3)];
            }
#pragma unroll
            for (int mt = 0; mt < 4; ++mt)
#pragma unroll
                for (int nt = 0; nt < 4; ++nt)
                    acc[mt][nt] = SWP
                        ? __builtin_amdgcn_mfma_f32_16x16x32_bf16(bf[nt], af[mt], acc[mt][nt], 0, 0, 0)
                        : __builtin_amdgcn_mfma_f32_16x16x32_bf16(af[mt], bf[nt], acc[mt][nt], 0, 0, 0);
        }
    }

    if (MODE == 0) {
        ushort_t* C = (ushort_t*)ga.C;
        const float os = ga.oscale;
#pragma unroll
        for (int mt = 0; mt < 4; ++mt) {
            int m = bm + mw + mt * 16 + lx;
#pragma unroll
            for (int nt = 0; nt < 4; ++nt) {
                int n0 = bn + nw + nt * 16 + quad * 4;
                uint2 u;
                u.x = pk2((acc[mt][nt][0] + b4[nt].x) * os, (acc[mt][nt][1] + b4[nt].y) * os);
                u.y = pk2((acc[mt][nt][2] + b4[nt].z) * os, (acc[mt][nt][3] + b4[nt].w) * os);
                *(uint2*)&C[(size_t)m * D_MODEL + n0] = u;
            }
        }
    } else if (MODE == 2) {
        float* C = (float*)ga.C;
#pragma unroll
        for (int mt = 0; mt < 4; ++mt) {
            int m = bm + mw + mt * 16 + lx;
#pragma unroll
            for (int nt = 0; nt < 4; ++nt) {
                int n0 = bn + nw + nt * 16 + quad * 4;
                float4 v;
                v.x = acc[mt][nt][0] + b4[nt].x;
                v.y = acc[mt][nt][1] + b4[nt].y;
                v.z = acc[mt][nt][2] + b4[nt].z;
                v.w = acc[mt][nt][3] + b4[nt].w;
                *(float4*)&C[(size_t)m * D_MODEL + n0] = v;
            }
        }
    } else {
        ushort_t* C = (ushort_t*)ga.C;
#pragma unroll
        for (int mt = 0; mt < 4; ++mt)
#pragma unroll
            for (int nt = 0; nt < 4; ++nt) {
                int n = bn + nw + nt * 16 + lx;
                int d = n & 63, h = n >> 6;
                int m0 = bm + mw + mt * 16 + quad * 4;
                int b = m0 >> 11, s0 = m0 & 2047;
                uint2 u;
                u.x = pk2(acc[mt][nt][0] + bfr[nt], acc[mt][nt][1] + bfr[nt]);
                u.y = pk2(acc[mt][nt][2] + bfr[nt], acc[mt][nt][3] + bfr[nt]);
                *(uint2*)&C[((size_t)(b * NHEADS + h) * DK + d) * SEQ + s0] = u;
            }
    }
}

__global__ __launch_bounds__(256) void gemm_mfma(GemmArgs g0, GemmArgs g1, GemmArgs g2)
{
    __shared__ ushort_t As0[128 * 64], Bs0[128 * 64];
    __shared__ ushort_t As1[128 * 64], Bs1[128 * 64];
    GemmArgs ga = (blockIdx.z == 0) ? g0 : ((blockIdx.z == 1) ? g1 : g2);
    if (ga.mode == 0)      gemm_core<0>(ga, As0, Bs0, As1, Bs1);
    else if (ga.mode == 1) gemm_core<1>(ga, As0, Bs0, As1, Bs1);
    else                   gemm_core<2>(ga, As0, Bs0, As1, Bs1);
}

// ---------------------------------------------------------------------------
// bf16 MFMA causal flash attention, paired q-tiles + double-buffered K/V
// (r7 body) + XCD-aware block mapping: all 16 pair-blocks of one (b,h) land
// on one XCD (bh>>2), so its K/V slice (512KB) stays L2-resident (4 slices =
// 2MB <= 4MB/XCD).  Grid: 512 blocks 1-D; id = xcd + 8*k, bh=(xcd<<2)|(k&3),
// p=k>>2.
// ---------------------------------------------------------------------------
__device__ __forceinline__ void flash_tile(
    int qt, const size_t qbase, const size_t vbase,
    const ushort_t* __restrict__ Qp, const ushort_t* __restrict__ Kp,
    const ushort_t* __restrict__ Vt, ushort_t* __restrict__ Hc,
    ushort_t* Ks0, ushort_t* Ks1, ushort_t* Vs0, ushort_t* Vs1,
    ushort_t (*Ps)[16 * 72])
{
    const int tid  = threadIdx.x;
    const int w    = tid >> 6, lane = tid & 63;
    const int quad = lane >> 4, lx = lane & 15;

    // ensure previous tile's consumers are done before overwriting buf0
    asm volatile("s_barrier" ::: "memory");

    // prologue: stage k-tile 0 into buffer 0
    {
#pragma unroll
        for (int i = 0; i < 2; ++i) {
            int r0 = (w + i * 4) * 8;
            int rl = r0 + (lane >> 3);
            int g  = (lane & 7) ^ (rl & 7);
            gll16(&Kp[qbase + (size_t)rl * D_MODEL + g * 8], &Ks0[r0 * 64]);
            gll16(&Vt[vbase + (size_t)rl * SEQ + g * 8], &Vs0[r0 * 64]);
        }
    }

    // Q fragments (row qt*64 + w*16 + lx), resident across all k-tiles
    short8 qf[2];
    {
        size_t ro = qbase + (size_t)(qt * 64 + w * 16 + lx) * D_MODEL + quad * 8;
        qf[0] = *(const short8*)&Qp[ro];
        qf[1] = *(const short8*)&Qp[ro + 32];
    }

    f32x4 O[4];           // O^T frags: d = nt*16+quad*4+r, q = lx
#pragma unroll
    for (int nt = 0; nt < 4; ++nt) O[nt] = (f32x4){0.f, 0.f, 0.f, 0.f};
    float mrow = -INFINITY, lrow = 0.f;   // per-lane state, q = lx
    const int qin = w * 16 + lx;          // q index within the 64-row tile

    for (int kt = 0; kt <= qt; ++kt) {
        ushort_t* Ks = (kt & 1) ? Ks1 : Ks0;
        ushort_t* Vs = (kt & 1) ? Vs1 : Vs0;

        // tile-kt loads were issued one full iteration ago
        asm volatile("s_waitcnt vmcnt(0)" ::: "memory");
        asm volatile("s_barrier" ::: "memory");

        // prefetch k-tile kt+1 into the other buffer (overlaps compute below)
        if (kt < qt) {
            ushort_t* Kn = (kt & 1) ? Ks0 : Ks1;
            ushort_t* Vn = (kt & 1) ? Vs0 : Vs1;
#pragma unroll
            for (int i = 0; i < 2; ++i) {
                int r0 = (w + i * 4) * 8;
                int rl = r0 + (lane >> 3);
                int g  = (lane & 7) ^ (rl & 7);
                gll16(&Kp[qbase + (size_t)((kt + 1) * 64 + rl) * D_MODEL + g * 8], &Kn[r0 * 64]);
                gll16(&Vt[vbase + (size_t)rl * SEQ + (kt + 1) * 64 + g * 8], &Vn[r0 * 64]);
            }
        }

        // S^T = K Q^T : s[nt][r] = S[q=lx][k = nt*16+quad*4+r]
        f32x4 s[4];
#pragma unroll
        for (int nt = 0; nt < 4; ++nt) {
            int r = nt * 16 + lx;
            short8 kf0 = *(const short8*)&Ks[r * 64 + ((quad ^ (r & 7)) << 3)];
            short8 kf1 = *(const short8*)&Ks[r * 64 + (((4 + quad) ^ (r & 7)) << 3)];
            f32x4 z = (f32x4){0.f, 0.f, 0.f, 0.f};
            z = __builtin_amdgcn_mfma_f32_16x16x32_bf16(kf0, qf[0], z, 0, 0, 0);
            z = __builtin_amdgcn_mfma_f32_16x16x32_bf16(kf1, qf[1], z, 0, 0, 0);
            s[nt] = z;
        }

        // causal mask (diagonal tile only); values already in log2 domain
        if (kt == qt) {
#pragma unroll
            for (int nt = 0; nt < 4; ++nt)
#pragma unroll
                for (int r = 0; r < 4; ++r)
                    if ((nt * 16 + quad * 4 + r) > qin) s[nt][r] = -INFINITY;
        }

        // online softmax: all 16 values are one q-row (q = lx)
        float tm = -INFINITY;
#pragma unroll
        for (int nt = 0; nt < 4; ++nt)
#pragma unroll
            for (int r = 0; r < 4; ++r) tm = fmaxf(tm, s[nt][r]);
        tm = fmaxf(tm, __shfl_xor(tm, 16, 64));
        tm = fmaxf(tm, __shfl_xor(tm, 32, 64));
        float mnew = fmaxf(mrow, tm);
        float alpha = __builtin_amdgcn_exp2f(mrow - mnew);
        mrow = mnew;
        float rs = 0.f;
#pragma unroll
        for (int nt = 0; nt < 4; ++nt)
#pragma unroll
            for (int r = 0; r < 4; ++r) {
                float p = __builtin_amdgcn_exp2f(s[nt][r] - mnew);
                s[nt][r] = p;
                rs += p;
            }
        rs += __shfl_xor(rs, 16, 64);
        rs += __shfl_xor(rs, 32, 64);
        lrow = lrow * alpha + rs;
#pragma unroll
        for (int nt = 0; nt < 4; ++nt)
#pragma unroll
            for (int r = 0; r < 4; ++r) O[nt][r] *= alpha;

        // P -> per-wave LDS, k-consecutive: one b64 per nt
#pragma unroll
        for (int nt = 0; nt < 4; ++nt) {
            uint2 u;
            u.x = pk2(s[nt][0], s[nt][1]);
            u.y = pk2(s[nt][2], s[nt][3]);
            *(uint2*)&Ps[w][lx * 72 + nt * 16 + quad * 4] = u;
        }

        // P A/B-frags (same-wave LDS RAW, in-order per wave)
        short8 pf0 = *(const short8*)&Ps[w][lx * 72 + quad * 8];
        short8 pf1 = *(const short8*)&Ps[w][lx * 72 + 32 + quad * 8];

        // O^T += V^T-frag x P-frag
#pragma unroll
        for (int nt = 0; nt < 4; ++nt) {
            int r = nt * 16 + lx;
            short8 vf0 = *(const short8*)&Vs[r * 64 + ((quad ^ (r & 7)) << 3)];
            short8 vf1 = *(const short8*)&Vs[r * 64 + (((4 + quad) ^ (r & 7)) << 3)];
            O[nt] = __builtin_amdgcn_mfma_f32_16x16x32_bf16(vf0, pf0, O[nt], 0, 0, 0);
            O[nt] = __builtin_amdgcn_mfma_f32_16x16x32_bf16(vf1, pf1, O[nt], 0, 0, 0);
        }
    }

    // epilogue: lane writes row q = lx, 4 consecutive d per nt (b64 stores)
    {
        float invl = 1.f / lrow;
        size_t ro = qbase + (size_t)(qt * 64 + w * 16 + lx) * D_MODEL;
#pragma unroll
        for (int nt = 0; nt < 4; ++nt) {
            uint2 u;
            u.x = pk2(O[nt][0] * invl, O[nt][1] * invl);
            u.y = pk2(O[nt][2] * invl, O[nt][3] * invl);
            *(uint2*)&Hc[ro + nt * 16 + quad * 4] = u;
        }
    }
}

__global__ __launch_bounds__(256) void flash_mfma(
    const ushort_t* __restrict__ Qp, const ushort_t* __restrict__ Kp,
    const ushort_t* __restrict__ Vt, ushort_t* __restrict__ Hc)
{
    // XCD-aware mapping: id = xcd + 8*k -> all blocks of one bh on one XCD
    const int id  = blockIdx.x;
    const int xcd = id & 7;
    const int k   = id >> 3;
    const int bh  = (xcd << 2) | (k & 3);   // 0..31
    const int p   = k >> 2;                 // pair index 0..15
    const int b = bh >> 4, h = bh & 15;

    __shared__ ushort_t Ks0[64 * 64], Ks1[64 * 64];
    __shared__ ushort_t Vs0[64 * 64], Vs1[64 * 64];
    __shared__ ushort_t Ps[4][16 * 72];   // per-wave P[q][k], stride 72

    const size_t qbase = (size_t)(b * SEQ) * D_MODEL + h * DK;
    const size_t vbase = (size_t)bh * DK * SEQ;

    // big tile first, then its small partner: exactly NQT+1 k-iters per block
    flash_tile(NQT - 1 - p, qbase, vbase, Qp, Kp, Vt, Hc, Ks0, Ks1, Vs0, Vs1, Ps);
    flash_tile(p,           qbase, vbase, Qp, Kp, Vt, Hc, Ks0, Ks1, Vs0, Vs1, Ps);
}

extern "C" void kernel_launch(void* const* d_in, const int* in_sizes, int n_in,
                              void* d_out, int out_size, void* d_ws, size_t ws_size,
                              hipStream_t stream) {
    const float* inQ = (const float*)d_in[0];
    const float* inK = (const float*)d_in[1];
    const float* inV = (const float*)d_in[2];
    const float* Wq  = (const float*)d_in[3];
    const float* bq  = (const float*)d_in[4];
    const float* Wk  = (const float*)d_in[5];
    const float* bk  = (const float*)d_in[6];
    const float* Wv  = (const float*)d_in[7];
    const float* bv  = (const float*)d_in[8];
    const float* Wo  = (const float*)d_in[9];
    const float* bo  = (const float*)d_in[10];
    float* out = (float*)d_out;

    const size_t NI = (size_t)MROWS * D_MODEL;      // 4M
    const size_t NW = (size_t)D_MODEL * D_MODEL;    // 1M
    ushort_t* ws  = (ushort_t*)d_ws;
    ushort_t* Qb  = ws;                // bf16 inputs
    ushort_t* Kb  = Qb  + NI;
    ushort_t* Vb  = Kb  + NI;
    ushort_t* Wqb = Vb  + NI;          // bf16 weights
    ushort_t* Wkb = Wqb + NW;
    ushort_t* Wvb = Wkb + NW;
    ushort_t* Wob = Wvb + NW;
    ushort_t* Qp  = Wob + NW;          // projections
    ushort_t* Kp  = Qp  + NI;
    ushort_t* Vtg = Kp  + NI;          // V^T [B*H][DK][SEQ]
    ushort_t* Hc  = Vtg + NI;

    // fp32 -> bf16 (all 7 tensors, one launch)
    cvt_bf16<<<dim3(NI / 1024, 7), 256, 0, stream>>>(
        inQ, inK, inV, Wq, Wk, Wv, Wo,
        Qb, Kb, Vb, Wqb, Wkb, Wvb, Wob, (int)NI, (int)NW);

    // fused QKV projection; Q pre-scaled by 1/sqrt(dk)*log2(e); V transposed
    const float qsc = 0.125f * 1.44269504088896340736f;
    GemmArgs aq{Qb, Wqb, bq, (void*)Qp, 0, qsc};
    GemmArgs ak{Kb, Wkb, bk, (void*)Kp, 0, 1.0f};
    GemmArgs av{Vb, Wvb, bv, (void*)Vtg, 1, 1.0f};
    gemm_mfma<<<dim3(MROWS / 128, D_MODEL / 128, 3), 256, 0, stream>>>(aq, ak, av);

    // attention (paired q-tiles, dbuf K/V pipeline, XCD-local L2)
    flash_mfma<<<dim3(NQT / 2 * BATCH * NHEADS), 256, 0, stream>>>(Qp, Kp, Vtg, Hc);

    // output projection (fp32 out)
    GemmArgs ao{Hc, Wob, bo, (void*)out, 2, 1.0f};
    gemm_mfma<<<dim3(MROWS / 128, D_MODEL / 128, 1), 256, 0, stream>>>(ao, ao, ao);
}

// Round 9
// 226.824 us; speedup vs baseline: 1.0075x; 1.0075x over previous
//
#include <hip/hip_runtime.h>
#include <hip/hip_bf16.h>
#include <math.h>

#define D_MODEL 1024
#define NHEADS  16
#define DK      64
#define SEQ     2048
#define BATCH   2
#define MROWS   4096   // BATCH*SEQ
#define NQT     (SEQ/64)   // 32 q-tiles

typedef unsigned short ushort_t;
using short8 = __attribute__((ext_vector_type(8))) short;
using f32x4  = __attribute__((ext_vector_type(4))) float;

__device__ __forceinline__ ushort_t f2bf(float x) {
    unsigned u = __float_as_uint(x);
    u = (u + 0x7FFFu + ((u >> 16) & 1u)) >> 16;   // RNE
    return (ushort_t)u;
}

// pack 2 floats -> 2 bf16 in one uint (v_cvt_pk_bf16_f32 on gfx950)
__device__ __forceinline__ unsigned pk2(float a, float b) {
    __hip_bfloat162 h = __float22bfloat162_rn(float2{a, b});
    unsigned u;
    __builtin_memcpy(&u, &h, 4);
    return u;
}

// async global->LDS, 16B per lane; LDS dest = wave-uniform base + lane*16
__device__ __forceinline__ void gll16(const ushort_t* g, ushort_t* l) {
    __builtin_amdgcn_global_load_lds(
        (const __attribute__((address_space(1))) void*)(g),
        (__attribute__((address_space(3))) void*)(l), 16, 0, 0);
}

// ---------------------------------------------------------------------------
// fp32 -> bf16 conversion, 7 tensors in one launch (blockIdx.y selects).
// ---------------------------------------------------------------------------
__global__ __launch_bounds__(256) void cvt_bf16(
    const float* s0, const float* s1, const float* s2, const float* s3,
    const float* s4, const float* s5, const float* s6,
    ushort_t* d0, ushort_t* d1, ushort_t* d2, ushort_t* d3,
    ushort_t* d4, ushort_t* d5, ushort_t* d6, int nIn, int nW)
{
    const float* s; ushort_t* d; int n;
    switch (blockIdx.y) {
        case 0: s = s0; d = d0; n = nIn; break;
        case 1: s = s1; d = d1; n = nIn; break;
        case 2: s = s2; d = d2; n = nIn; break;
        case 3: s = s3; d = d3; n = nW;  break;
        case 4: s = s4; d = d4; n = nW;  break;
        case 5: s = s5; d = d5; n = nW;  break;
        default: s = s6; d = d6; n = nW; break;
    }
    int i = (blockIdx.x * 256 + threadIdx.x) * 4;
    if (i < n) {
        float4 v = *(const float4*)&s[i];
        ushort4 o;
        o.x = f2bf(v.x); o.y = f2bf(v.y); o.z = f2bf(v.z); o.w = f2bf(v.w);
        *(ushort4*)&d[i] = o;
    }
}

// ---------------------------------------------------------------------------
// bf16 MFMA GEMM (QKV):  C[M,N] = (A @ W^T + bias) * oscale
// 128x128 tile, BK=64, dbuf global_load_lds pipeline (raw s_barrier + vmcnt).
// MODE 0: bf16 row-major out.  MODE 1: bf16 transposed out [B*H][DK][SEQ].
// ---------------------------------------------------------------------------
struct GemmArgs { const ushort_t* A; const ushort_t* W; const float* bias;
                  void* C; int mode; float oscale; };

template<int MODE>
__device__ __forceinline__ void gemm_core(const GemmArgs& ga,
                                          ushort_t* As0, ushort_t* Bs0,
                                          ushort_t* As1, ushort_t* Bs1)
{
    constexpr bool SWP = (MODE != 1);
    const int tid  = threadIdx.x;
    const int w    = tid >> 6, lane = tid & 63;
    const int quad = lane >> 4, lx = lane & 15;
    const int mw = (w >> 1) * 64, nw = (w & 1) * 64;
    const int bm = blockIdx.x * 128, bn = blockIdx.y * 128;
    const int K = D_MODEL;

    auto stage = [&](int k0, ushort_t* As, ushort_t* Bs) {
#pragma unroll
        for (int i = 0; i < 4; ++i) {
            int r0 = (w * 4 + i) * 8;
            int rl = r0 + (lane >> 3);
            int g  = (lane & 7) ^ (rl & 7);
            gll16(&ga.A[(size_t)(bm + rl) * K + k0 + g * 8], &As[r0 * 64]);
            gll16(&ga.W[(size_t)(bn + rl) * K + k0 + g * 8], &Bs[r0 * 64]);
        }
    };

    f32x4 acc[4][4];
#pragma unroll
    for (int mt = 0; mt < 4; ++mt)
#pragma unroll
        for (int nt = 0; nt < 4; ++nt)
            acc[mt][nt] = (f32x4){0.f, 0.f, 0.f, 0.f};

    float4 b4[4];
    float  bfr[4];
#pragma unroll
    for (int nt = 0; nt < 4; ++nt) {
        if (SWP) b4[nt] = *(const float4*)&ga.bias[bn + nw + nt * 16 + quad * 4];
        else     bfr[nt] = ga.bias[bn + nw + nt * 16 + lx];
    }

    stage(0, As0, Bs0);

    for (int it = 0; it < K / 64; ++it) {
        ushort_t* As = (it & 1) ? As1 : As0;
        ushort_t* Bs = (it & 1) ? Bs1 : Bs0;

        asm volatile("s_waitcnt vmcnt(0)" ::: "memory");
        asm volatile("s_barrier" ::: "memory");

        if (it + 1 < K / 64)
            stage((it + 1) * 64, (it & 1) ? As0 : As1, (it & 1) ? Bs0 : Bs1);

#pragma unroll
        for (int ks = 0; ks < 2; ++ks) {
            short8 af[4], bf[4];
#pragma unroll
            for (int mt = 0; mt < 4; ++mt) {
                int r = mw + mt * 16 + lx;
                af[mt] = *(const short8*)&As[r * 64 + (((ks * 4 + quad) ^ (r & 7)) << 3)];
            }
#pragma unroll
            for (int nt = 0; nt < 4; ++nt) {
                int r = nw + nt * 16 + lx;
                bf[nt] = *(const short8*)&Bs[r * 64 + (((ks * 4 + quad) ^ (r & 7)) << 3)];
            }
#pragma unroll
            for (int mt = 0; mt < 4; ++mt)
#pragma unroll
                for (int nt = 0; nt < 4; ++nt)
                    acc[mt][nt] = SWP
                        ? __builtin_amdgcn_mfma_f32_16x16x32_bf16(bf[nt], af[mt], acc[mt][nt], 0, 0, 0)
                        : __builtin_amdgcn_mfma_f32_16x16x32_bf16(af[mt], bf[nt], acc[mt][nt], 0, 0, 0);
        }
    }

    if (MODE == 0) {
        ushort_t* C = (ushort_t*)ga.C;
        const float os = ga.oscale;
#pragma unroll
        for (int mt = 0; mt < 4; ++mt) {
            int m = bm + mw + mt * 16 + lx;
#pragma unroll
            for (int nt = 0; nt < 4; ++nt) {
                int n0 = bn + nw + nt * 16 + quad * 4;
                uint2 u;
                u.x = pk2((acc[mt][nt][0] + b4[nt].x) * os, (acc[mt][nt][1] + b4[nt].y) * os);
                u.y = pk2((acc[mt][nt][2] + b4[nt].z) * os, (acc[mt][nt][3] + b4[nt].w) * os);
                *(uint2*)&C[(size_t)m * D_MODEL + n0] = u;
            }
        }
    } else {
        ushort_t* C = (ushort_t*)ga.C;
#pragma unroll
        for (int mt = 0; mt < 4; ++mt)
#pragma unroll
            for (int nt = 0; nt < 4; ++nt) {
                int n = bn + nw + nt * 16 + lx;
                int d = n & 63, h = n >> 6;
                int m0 = bm + mw + mt * 16 + quad * 4;
                int b = m0 >> 11, s0 = m0 & 2047;
                uint2 u;
                u.x = pk2(acc[mt][nt][0] + bfr[nt], acc[mt][nt][1] + bfr[nt]);
                u.y = pk2(acc[mt][nt][2] + bfr[nt], acc[mt][nt][3] + bfr[nt]);
                *(uint2*)&C[((size_t)(b * NHEADS + h) * DK + d) * SEQ + s0] = u;
            }
    }
}

__global__ __launch_bounds__(256) void gemm_mfma(GemmArgs g0, GemmArgs g1, GemmArgs g2)
{
    __shared__ ushort_t As0[128 * 64], Bs0[128 * 64];
    __shared__ ushort_t As1[128 * 64], Bs1[128 * 64];
    GemmArgs ga = (blockIdx.z == 0) ? g0 : ((blockIdx.z == 1) ? g1 : g2);
    if (ga.mode == 0) gemm_core<0>(ga, As0, Bs0, As1, Bs1);
    else              gemm_core<1>(ga, As0, Bs0, As1, Bs1);
}

// ---------------------------------------------------------------------------
// O-projection GEMM: out[M,N] = Hc @ Wo^T + bo, fp32 out.
// 64x128 tile (waves 2x2, each 32x64, acc[2][4]) -> grid 64x8 = 512 blocks
// = 2 blocks/CU (vs 1 for the 128x128 version): restores cross-block TLP.
// dbuf LDS 48KB, same raw-barrier vmcnt pipeline.
// ---------------------------------------------------------------------------
__global__ __launch_bounds__(256) void gemm_o(
    const ushort_t* __restrict__ A, const ushort_t* __restrict__ W,
    const float* __restrict__ bias, float* __restrict__ C)
{
    __shared__ ushort_t As0[64 * 64],  As1[64 * 64];
    __shared__ ushort_t Bs0[128 * 64], Bs1[128 * 64];

    const int tid  = threadIdx.x;
    const int w    = tid >> 6, lane = tid & 63;
    const int quad = lane >> 4, lx = lane & 15;
    const int mw = (w >> 1) * 32, nw = (w & 1) * 64;
    const int bm = blockIdx.x * 64, bn = blockIdx.y * 128;
    const int K = D_MODEL;

    auto stage = [&](int k0, ushort_t* As, ushort_t* Bs) {
#pragma unroll
        for (int i = 0; i < 2; ++i) {
            int r0 = (i * 4 + w) * 8;
            int rl = r0 + (lane >> 3);
            int g  = (lane & 7) ^ (rl & 7);
            gll16(&A[(size_t)(bm + rl) * K + k0 + g * 8], &As[r0 * 64]);
        }
#pragma unroll
        for (int i = 0; i < 4; ++i) {
            int r0 = (i * 4 + w) * 8;
            int rl = r0 + (lane >> 3);
            int g  = (lane & 7) ^ (rl & 7);
            gll16(&W[(size_t)(bn + rl) * K + k0 + g * 8], &Bs[r0 * 64]);
        }
    };

    f32x4 acc[2][4];
#pragma unroll
    for (int mt = 0; mt < 2; ++mt)
#pragma unroll
        for (int nt = 0; nt < 4; ++nt)
            acc[mt][nt] = (f32x4){0.f, 0.f, 0.f, 0.f};

    float4 b4[4];
#pragma unroll
    for (int nt = 0; nt < 4; ++nt)
        b4[nt] = *(const float4*)&bias[bn + nw + nt * 16 + quad * 4];

    stage(0, As0, Bs0);

    for (int it = 0; it < K / 64; ++it) {
        ushort_t* As = (it & 1) ? As1 : As0;
        ushort_t* Bs = (it & 1) ? Bs1 : Bs0;

        asm volatile("s_waitcnt vmcnt(0)" ::: "memory");
        asm volatile("s_barrier" ::: "memory");

        if (it + 1 < K / 64)
            stage((it + 1) * 64, (it & 1) ? As0 : As1, (it & 1) ? Bs0 : Bs1);

#pragma unroll
        for (int ks = 0; ks < 2; ++ks) {
            short8 af[2], bf[4];
#pragma unroll
            for (int mt = 0; mt < 2; ++mt) {
                int r = mw + mt * 16 + lx;
                af[mt] = *(const short8*)&As[r * 64 + (((ks * 4 + quad) ^ (r & 7)) << 3)];
            }
#pragma unroll
            for (int nt = 0; nt < 4; ++nt) {
                int r = nw + nt * 16 + lx;
                bf[nt] = *(const short8*)&Bs[r * 64 + (((ks * 4 + quad) ^ (r & 7)) << 3)];
            }
#pragma unroll
            for (int mt = 0; mt < 2; ++mt)
#pragma unroll
                for (int nt = 0; nt < 4; ++nt)
                    acc[mt][nt] = __builtin_amdgcn_mfma_f32_16x16x32_bf16(
                        bf[nt], af[mt], acc[mt][nt], 0, 0, 0);
        }
    }

    // epilogue: swapped layout -> lane holds m = ..+lx, 4 consec n (float4)
#pragma unroll
    for (int mt = 0; mt < 2; ++mt) {
        int m = bm + mw + mt * 16 + lx;
#pragma unroll
        for (int nt = 0; nt < 4; ++nt) {
            int n0 = bn + nw + nt * 16 + quad * 4;
            float4 v;
            v.x = acc[mt][nt][0] + b4[nt].x;
            v.y = acc[mt][nt][1] + b4[nt].y;
            v.z = acc[mt][nt][2] + b4[nt].z;
            v.w = acc[mt][nt][3] + b4[nt].w;
            *(float4*)&C[(size_t)m * D_MODEL + n0] = v;
        }
    }
}

// ---------------------------------------------------------------------------
// bf16 MFMA causal flash attention, paired q-tiles + double-buffered K/V
// (r7 configuration: plain 2-D grid).
// ---------------------------------------------------------------------------
__device__ __forceinline__ void flash_tile(
    int qt, const size_t qbase, const size_t vbase,
    const ushort_t* __restrict__ Qp, const ushort_t* __restrict__ Kp,
    const ushort_t* __restrict__ Vt, ushort_t* __restrict__ Hc,
    ushort_t* Ks0, ushort_t* Ks1, ushort_t* Vs0, ushort_t* Vs1,
    ushort_t (*Ps)[16 * 72])
{
    const int tid  = threadIdx.x;
    const int w    = tid >> 6, lane = tid & 63;
    const int quad = lane >> 4, lx = lane & 15;

    // ensure previous tile's consumers are done before overwriting buf0
    asm volatile("s_barrier" ::: "memory");

    // prologue: stage k-tile 0 into buffer 0
    {
#pragma unroll
        for (int i = 0; i < 2; ++i) {
            int r0 = (w + i * 4) * 8;
            int rl = r0 + (lane >> 3);
            int g  = (lane & 7) ^ (rl & 7);
            gll16(&Kp[qbase + (size_t)rl * D_MODEL + g * 8], &Ks0[r0 * 64]);
            gll16(&Vt[vbase + (size_t)rl * SEQ + g * 8], &Vs0[r0 * 64]);
        }
    }

    // Q fragments (row qt*64 + w*16 + lx), resident across all k-tiles
    short8 qf[2];
    {
        size_t ro = qbase + (size_t)(qt * 64 + w * 16 + lx) * D_MODEL + quad * 8;
        qf[0] = *(const short8*)&Qp[ro];
        qf[1] = *(const short8*)&Qp[ro + 32];
    }

    f32x4 O[4];           // O^T frags: d = nt*16+quad*4+r, q = lx
#pragma unroll
    for (int nt = 0; nt < 4; ++nt) O[nt] = (f32x4){0.f, 0.f, 0.f, 0.f};
    float mrow = -INFINITY, lrow = 0.f;   // per-lane state, q = lx
    const int qin = w * 16 + lx;          // q index within the 64-row tile

    for (int kt = 0; kt <= qt; ++kt) {
        ushort_t* Ks = (kt & 1) ? Ks1 : Ks0;
        ushort_t* Vs = (kt & 1) ? Vs1 : Vs0;

        // tile-kt loads were issued one full iteration ago
        asm volatile("s_waitcnt vmcnt(0)" ::: "memory");
        asm volatile("s_barrier" ::: "memory");

        // prefetch k-tile kt+1 into the other buffer (overlaps compute below)
        if (kt < qt) {
            ushort_t* Kn = (kt & 1) ? Ks0 : Ks1;
            ushort_t* Vn = (kt & 1) ? Vs0 : Vs1;
#pragma unroll
            for (int i = 0; i < 2; ++i) {
                int r0 = (w + i * 4) * 8;
                int rl = r0 + (lane >> 3);
                int g  = (lane & 7) ^ (rl & 7);
                gll16(&Kp[qbase + (size_t)((kt + 1) * 64 + rl) * D_MODEL + g * 8], &Kn[r0 * 64]);
                gll16(&Vt[vbase + (size_t)rl * SEQ + (kt + 1) * 64 + g * 8], &Vn[r0 * 64]);
            }
        }

        // S^T = K Q^T : s[nt][r] = S[q=lx][k = nt*16+quad*4+r]
        f32x4 s[4];
#pragma unroll
        for (int nt = 0; nt < 4; ++nt) {
            int r = nt * 16 + lx;
            short8 kf0 = *(const short8*)&Ks[r * 64 + ((quad ^ (r & 7)) << 3)];
            short8 kf1 = *(const short8*)&Ks[r * 64 + (((4 + quad) ^ (r & 7)) << 3)];
            f32x4 z = (f32x4){0.f, 0.f, 0.f, 0.f};
            z = __builtin_amdgcn_mfma_f32_16x16x32_bf16(kf0, qf[0], z, 0, 0, 0);
            z = __builtin_amdgcn_mfma_f32_16x16x32_bf16(kf1, qf[1], z, 0, 0, 0);
            s[nt] = z;
        }

        // causal mask (diagonal tile only); values already in log2 domain
        if (kt == qt) {
#pragma unroll
            for (int nt = 0; nt < 4; ++nt)
#pragma unroll
                for (int r = 0; r < 4; ++r)
                    if ((nt * 16 + quad * 4 + r) > qin) s[nt][r] = -INFINITY;
        }

        // online softmax: all 16 values are one q-row (q = lx)
        float tm = -INFINITY;
#pragma unroll
        for (int nt = 0; nt < 4; ++nt)
#pragma unroll
            for (int r = 0; r < 4; ++r) tm = fmaxf(tm, s[nt][r]);
        tm = fmaxf(tm, __shfl_xor(tm, 16, 64));
        tm = fmaxf(tm, __shfl_xor(tm, 32, 64));
        float mnew = fmaxf(mrow, tm);
        float alpha = __builtin_amdgcn_exp2f(mrow - mnew);
        mrow = mnew;
        float rs = 0.f;
#pragma unroll
        for (int nt = 0; nt < 4; ++nt)
#pragma unroll
            for (int r = 0; r < 4; ++r) {
                float p = __builtin_amdgcn_exp2f(s[nt][r] - mnew);
                s[nt][r] = p;
                rs += p;
            }
        rs += __shfl_xor(rs, 16, 64);
        rs += __shfl_xor(rs, 32, 64);
        lrow = lrow * alpha + rs;
#pragma unroll
        for (int nt = 0; nt < 4; ++nt)
#pragma unroll
            for (int r = 0; r < 4; ++r) O[nt][r] *= alpha;

        // P -> per-wave LDS, k-consecutive: one b64 per nt
#pragma unroll
        for (int nt = 0; nt < 4; ++nt) {
            uint2 u;
            u.x = pk2(s[nt][0], s[nt][1]);
            u.y = pk2(s[nt][2], s[nt][3]);
            *(uint2*)&Ps[w][lx * 72 + nt * 16 + quad * 4] = u;
        }

        // P A/B-frags (same-wave LDS RAW, in-order per wave)
        short8 pf0 = *(const short8*)&Ps[w][lx * 72 + quad * 8];
        short8 pf1 = *(const short8*)&Ps[w][lx * 72 + 32 + quad * 8];

        // O^T += V^T-frag x P-frag
#pragma unroll
        for (int nt = 0; nt < 4; ++nt) {
            int r = nt * 16 + lx;
            short8 vf0 = *(const short8*)&Vs[r * 64 + ((quad ^ (r & 7)) << 3)];
            short8 vf1 = *(const short8*)&Vs[r * 64 + (((4 + quad) ^ (r & 7)) << 3)];
            O[nt] = __builtin_amdgcn_mfma_f32_16x16x32_bf16(vf0, pf0, O[nt], 0, 0, 0);
            O[nt] = __builtin_amdgcn_mfma_f32_16x16x32_bf16(vf1, pf1, O[nt], 0, 0, 0);
        }
    }

    // epilogue: lane writes row q = lx, 4 consecutive d per nt (b64 stores)
    {
        float invl = 1.f / lrow;
        size_t ro = qbase + (size_t)(qt * 64 + w * 16 + lx) * D_MODEL;
#pragma unroll
        for (int nt = 0; nt < 4; ++nt) {
            uint2 u;
            u.x = pk2(O[nt][0] * invl, O[nt][1] * invl);
            u.y = pk2(O[nt][2] * invl, O[nt][3] * invl);
            *(uint2*)&Hc[ro + nt * 16 + quad * 4] = u;
        }
    }
}

__global__ __launch_bounds__(256) void flash_mfma(
    const ushort_t* __restrict__ Qp, const ushort_t* __restrict__ Kp,
    const ushort_t* __restrict__ Vt, ushort_t* __restrict__ Hc)
{
    const int p  = blockIdx.x;            // pair index 0..NQT/2-1
    const int bh = blockIdx.y;
    const int b = bh >> 4, h = bh & 15;

    __shared__ ushort_t Ks0[64 * 64], Ks1[64 * 64];
    __shared__ ushort_t Vs0[64 * 64], Vs1[64 * 64];
    __shared__ ushort_t Ps[4][16 * 72];   // per-wave P[q][k], stride 72

    const size_t qbase = (size_t)(b * SEQ) * D_MODEL + h * DK;
    const size_t vbase = (size_t)bh * DK * SEQ;

    // big tile first, then its small partner: exactly NQT+1 k-iters per block
    flash_tile(NQT - 1 - p, qbase, vbase, Qp, Kp, Vt, Hc, Ks0, Ks1, Vs0, Vs1, Ps);
    flash_tile(p,           qbase, vbase, Qp, Kp, Vt, Hc, Ks0, Ks1, Vs0, Vs1, Ps);
}

extern "C" void kernel_launch(void* const* d_in, const int* in_sizes, int n_in,
                              void* d_out, int out_size, void* d_ws, size_t ws_size,
                              hipStream_t stream) {
    const float* inQ = (const float*)d_in[0];
    const float* inK = (const float*)d_in[1];
    const float* inV = (const float*)d_in[2];
    const float* Wq  = (const float*)d_in[3];
    const float* bq  = (const float*)d_in[4];
    const float* Wk  = (const float*)d_in[5];
    const float* bk  = (const float*)d_in[6];
    const float* Wv  = (const float*)d_in[7];
    const float* bv  = (const float*)d_in[8];
    const float* Wo  = (const float*)d_in[9];
    const float* bo  = (const float*)d_in[10];
    float* out = (float*)d_out;

    const size_t NI = (size_t)MROWS * D_MODEL;      // 4M
    const size_t NW = (size_t)D_MODEL * D_MODEL;    // 1M
    ushort_t* ws  = (ushort_t*)d_ws;
    ushort_t* Qb  = ws;                // bf16 inputs
    ushort_t* Kb  = Qb  + NI;
    ushort_t* Vb  = Kb  + NI;
    ushort_t* Wqb = Vb  + NI;          // bf16 weights
    ushort_t* Wkb = Wqb + NW;
    ushort_t* Wvb = Wkb + NW;
    ushort_t* Wob = Wvb + NW;
    ushort_t* Qp  = Wob + NW;          // projections
    ushort_t* Kp  = Qp  + NI;
    ushort_t* Vtg = Kp  + NI;          // V^T [B*H][DK][SEQ]
    ushort_t* Hc  = Vtg + NI;

    // fp32 -> bf16 (all 7 tensors, one launch)
    cvt_bf16<<<dim3(NI / 1024, 7), 256, 0, stream>>>(
        inQ, inK, inV, Wq, Wk, Wv, Wo,
        Qb, Kb, Vb, Wqb, Wkb, Wvb, Wob, (int)NI, (int)NW);

    // fused QKV projection; Q pre-scaled by 1/sqrt(dk)*log2(e); V transposed
    const float qsc = 0.125f * 1.44269504088896340736f;
    GemmArgs aq{Qb, Wqb, bq, (void*)Qp, 0, qsc};
    GemmArgs ak{Kb, Wkb, bk, (void*)Kp, 0, 1.0f};
    GemmArgs av{Vb, Wvb, bv, (void*)Vtg, 1, 1.0f};
    gemm_mfma<<<dim3(MROWS / 128, D_MODEL / 128, 3), 256, 0, stream>>>(aq, ak, av);

    // attention (paired q-tiles, dbuf K/V pipeline)
    flash_mfma<<<dim3(NQT / 2, BATCH * NHEADS), 256, 0, stream>>>(Qp, Kp, Vtg, Hc);

    // output projection (fp32 out), 64x128 tiles -> 512 blocks = 2/CU
    gemm_o<<<dim3(MROWS / 64, D_MODEL / 128), 256, 0, stream>>>(Hc, Wob, bo, out);
}

// Round 10
// 220.750 us; speedup vs baseline: 1.0352x; 1.0275x over previous
//
#include <hip/hip_runtime.h>
#include <hip/hip_bf16.h>
#include <math.h>

#define D_MODEL 1024
#define NHEADS  16
#define DK      64
#define SEQ     2048
#define BATCH   2
#define MROWS   4096   // BATCH*SEQ
#define NQT     (SEQ/64)   // 32 q-tiles

typedef unsigned short ushort_t;
using short8 = __attribute__((ext_vector_type(8))) short;
using f32x4  = __attribute__((ext_vector_type(4))) float;

__device__ __forceinline__ ushort_t f2bf(float x) {
    unsigned u = __float_as_uint(x);
    u = (u + 0x7FFFu + ((u >> 16) & 1u)) >> 16;   // RNE
    return (ushort_t)u;
}

// pack 2 floats -> 2 bf16 in one uint (v_cvt_pk_bf16_f32 on gfx950)
__device__ __forceinline__ unsigned pk2(float a, float b) {
    __hip_bfloat162 h = __float22bfloat162_rn(float2{a, b});
    unsigned u;
    __builtin_memcpy(&u, &h, 4);
    return u;
}

// async global->LDS, 16B per lane; LDS dest = wave-uniform base + lane*16
__device__ __forceinline__ void gll16(const ushort_t* g, ushort_t* l) {
    __builtin_amdgcn_global_load_lds(
        (const __attribute__((address_space(1))) void*)(g),
        (__attribute__((address_space(3))) void*)(l), 16, 0, 0);
}

// ---------------------------------------------------------------------------
// fp32 -> bf16 conversion, 7 tensors in one launch (blockIdx.y selects).
// ---------------------------------------------------------------------------
__global__ __launch_bounds__(256) void cvt_bf16(
    const float* s0, const float* s1, const float* s2, const float* s3,
    const float* s4, const float* s5, const float* s6,
    ushort_t* d0, ushort_t* d1, ushort_t* d2, ushort_t* d3,
    ushort_t* d4, ushort_t* d5, ushort_t* d6, int nIn, int nW)
{
    const float* s; ushort_t* d; int n;
    switch (blockIdx.y) {
        case 0: s = s0; d = d0; n = nIn; break;
        case 1: s = s1; d = d1; n = nIn; break;
        case 2: s = s2; d = d2; n = nIn; break;
        case 3: s = s3; d = d3; n = nW;  break;
        case 4: s = s4; d = d4; n = nW;  break;
        case 5: s = s5; d = d5; n = nW;  break;
        default: s = s6; d = d6; n = nW; break;
    }
    int i = (blockIdx.x * 256 + threadIdx.x) * 4;
    if (i < n) {
        float4 v = *(const float4*)&s[i];
        ushort4 o;
        o.x = f2bf(v.x); o.y = f2bf(v.y); o.z = f2bf(v.z); o.w = f2bf(v.w);
        *(ushort4*)&d[i] = o;
    }
}

// ---------------------------------------------------------------------------
// bf16 MFMA GEMM (QKV):  C[M,N] = (A @ W^T + bias) * oscale
// 128x128 tile, BK=64, SINGLE-buffered global_load_lds (r7 structure —
// 32KB LDS keeps 3+ blocks/CU co-resident; wave-level overlap hides the
// barrier drain better than an explicit dbuf at 2/CU, measured r7 vs r8).
// MODE 0: bf16 row-major out.  MODE 1: bf16 transposed out [B*H][DK][SEQ].
// ---------------------------------------------------------------------------
struct GemmArgs { const ushort_t* A; const ushort_t* W; const float* bias;
                  void* C; int mode; float oscale; };

template<int MODE>
__device__ __forceinline__ void gemm_core(const GemmArgs& ga,
                                          ushort_t* As, ushort_t* Bs)
{
    constexpr bool SWP = (MODE != 1);
    const int tid  = threadIdx.x;
    const int w    = tid >> 6, lane = tid & 63;
    const int quad = lane >> 4, lx = lane & 15;
    const int mw = (w >> 1) * 64, nw = (w & 1) * 64;
    const int bm = blockIdx.x * 128, bn = blockIdx.y * 128;
    const int K = D_MODEL;

    f32x4 acc[4][4];
#pragma unroll
    for (int mt = 0; mt < 4; ++mt)
#pragma unroll
        for (int nt = 0; nt < 4; ++nt)
            acc[mt][nt] = (f32x4){0.f, 0.f, 0.f, 0.f};

    float4 b4[4];
    float  bfr[4];
#pragma unroll
    for (int nt = 0; nt < 4; ++nt) {
        if (SWP) b4[nt] = *(const float4*)&ga.bias[bn + nw + nt * 16 + quad * 4];
        else     bfr[nt] = ga.bias[bn + nw + nt * 16 + lx];
    }

    for (int k0 = 0; k0 < K; k0 += 64) {
        __syncthreads();
#pragma unroll
        for (int i = 0; i < 4; ++i) {
            int r0 = (w * 4 + i) * 8;
            int rl = r0 + (lane >> 3);
            int g  = (lane & 7) ^ (rl & 7);
            gll16(&ga.A[(size_t)(bm + rl) * K + k0 + g * 8], &As[r0 * 64]);
            gll16(&ga.W[(size_t)(bn + rl) * K + k0 + g * 8], &Bs[r0 * 64]);
        }
        __syncthreads();

#pragma unroll
        for (int ks = 0; ks < 2; ++ks) {
            short8 af[4], bf[4];
#pragma unroll
            for (int mt = 0; mt < 4; ++mt) {
                int r = mw + mt * 16 + lx;
                af[mt] = *(const short8*)&As[r * 64 + (((ks * 4 + quad) ^ (r & 7)) << 3)];
            }
#pragma unroll
            for (int nt = 0; nt < 4; ++nt) {
                int r = nw + nt * 16 + lx;
                bf[nt] = *(const short8*)&Bs[r * 64 + (((ks * 4 + quad) ^ (r & 7)) << 3)];
            }
#pragma unroll
            for (int mt = 0; mt < 4; ++mt)
#pragma unroll
                for (int nt = 0; nt < 4; ++nt)
                    acc[mt][nt] = SWP
                        ? __builtin_amdgcn_mfma_f32_16x16x32_bf16(bf[nt], af[mt], acc[mt][nt], 0, 0, 0)
                        : __builtin_amdgcn_mfma_f32_16x16x32_bf16(af[mt], bf[nt], acc[mt][nt], 0, 0, 0);
        }
    }

    if (MODE == 0) {
        ushort_t* C = (ushort_t*)ga.C;
        const float os = ga.oscale;
#pragma unroll
        for (int mt = 0; mt < 4; ++mt) {
            int m = bm + mw + mt * 16 + lx;
#pragma unroll
            for (int nt = 0; nt < 4; ++nt) {
                int n0 = bn + nw + nt * 16 + quad * 4;
                uint2 u;
                u.x = pk2((acc[mt][nt][0] + b4[nt].x) * os, (acc[mt][nt][1] + b4[nt].y) * os);
                u.y = pk2((acc[mt][nt][2] + b4[nt].z) * os, (acc[mt][nt][3] + b4[nt].w) * os);
                *(uint2*)&C[(size_t)m * D_MODEL + n0] = u;
            }
        }
    } else {
        ushort_t* C = (ushort_t*)ga.C;
#pragma unroll
        for (int mt = 0; mt < 4; ++mt)
#pragma unroll
            for (int nt = 0; nt < 4; ++nt) {
                int n = bn + nw + nt * 16 + lx;
                int d = n & 63, h = n >> 6;
                int m0 = bm + mw + mt * 16 + quad * 4;
                int b = m0 >> 11, s0 = m0 & 2047;
                uint2 u;
                u.x = pk2(acc[mt][nt][0] + bfr[nt], acc[mt][nt][1] + bfr[nt]);
                u.y = pk2(acc[mt][nt][2] + bfr[nt], acc[mt][nt][3] + bfr[nt]);
                *(uint2*)&C[((size_t)(b * NHEADS + h) * DK + d) * SEQ + s0] = u;
            }
    }
}

__global__ __launch_bounds__(256) void gemm_mfma(GemmArgs g0, GemmArgs g1, GemmArgs g2)
{
    __shared__ ushort_t As[128 * 64];
    __shared__ ushort_t Bs[128 * 64];
    GemmArgs ga = (blockIdx.z == 0) ? g0 : ((blockIdx.z == 1) ? g1 : g2);
    if (ga.mode == 0) gemm_core<0>(ga, As, Bs);
    else              gemm_core<1>(ga, As, Bs);
}

// ---------------------------------------------------------------------------
// O-projection GEMM: out[M,N] = Hc @ Wo^T + bo, fp32 out.
// 64x128 tile (waves 2x2, each 32x64), SINGLE-buffered (24KB LDS), grid
// 64x8 = 512 blocks = 2/CU with headroom for more co-residency.
// ---------------------------------------------------------------------------
__global__ __launch_bounds__(256) void gemm_o(
    const ushort_t* __restrict__ A, const ushort_t* __restrict__ W,
    const float* __restrict__ bias, float* __restrict__ C)
{
    __shared__ ushort_t As[64 * 64];
    __shared__ ushort_t Bs[128 * 64];

    const int tid  = threadIdx.x;
    const int w    = tid >> 6, lane = tid & 63;
    const int quad = lane >> 4, lx = lane & 15;
    const int mw = (w >> 1) * 32, nw = (w & 1) * 64;
    const int bm = blockIdx.x * 64, bn = blockIdx.y * 128;
    const int K = D_MODEL;

    f32x4 acc[2][4];
#pragma unroll
    for (int mt = 0; mt < 2; ++mt)
#pragma unroll
        for (int nt = 0; nt < 4; ++nt)
            acc[mt][nt] = (f32x4){0.f, 0.f, 0.f, 0.f};

    float4 b4[4];
#pragma unroll
    for (int nt = 0; nt < 4; ++nt)
        b4[nt] = *(const float4*)&bias[bn + nw + nt * 16 + quad * 4];

    for (int k0 = 0; k0 < K; k0 += 64) {
        __syncthreads();
#pragma unroll
        for (int i = 0; i < 2; ++i) {
            int r0 = (i * 4 + w) * 8;
            int rl = r0 + (lane >> 3);
            int g  = (lane & 7) ^ (rl & 7);
            gll16(&A[(size_t)(bm + rl) * K + k0 + g * 8], &As[r0 * 64]);
        }
#pragma unroll
        for (int i = 0; i < 4; ++i) {
            int r0 = (i * 4 + w) * 8;
            int rl = r0 + (lane >> 3);
            int g  = (lane & 7) ^ (rl & 7);
            gll16(&W[(size_t)(bn + rl) * K + k0 + g * 8], &Bs[r0 * 64]);
        }
        __syncthreads();

#pragma unroll
        for (int ks = 0; ks < 2; ++ks) {
            short8 af[2], bf[4];
#pragma unroll
            for (int mt = 0; mt < 2; ++mt) {
                int r = mw + mt * 16 + lx;
                af[mt] = *(const short8*)&As[r * 64 + (((ks * 4 + quad) ^ (r & 7)) << 3)];
            }
#pragma unroll
            for (int nt = 0; nt < 4; ++nt) {
                int r = nw + nt * 16 + lx;
                bf[nt] = *(const short8*)&Bs[r * 64 + (((ks * 4 + quad) ^ (r & 7)) << 3)];
            }
#pragma unroll
            for (int mt = 0; mt < 2; ++mt)
#pragma unroll
                for (int nt = 0; nt < 4; ++nt)
                    acc[mt][nt] = __builtin_amdgcn_mfma_f32_16x16x32_bf16(
                        bf[nt], af[mt], acc[mt][nt], 0, 0, 0);
        }
    }

    // epilogue: swapped layout -> lane holds m = ..+lx, 4 consec n (float4)
#pragma unroll
    for (int mt = 0; mt < 2; ++mt) {
        int m = bm + mw + mt * 16 + lx;
#pragma unroll
        for (int nt = 0; nt < 4; ++nt) {
            int n0 = bn + nw + nt * 16 + quad * 4;
            float4 v;
            v.x = acc[mt][nt][0] + b4[nt].x;
            v.y = acc[mt][nt][1] + b4[nt].y;
            v.z = acc[mt][nt][2] + b4[nt].z;
            v.w = acc[mt][nt][3] + b4[nt].w;
            *(float4*)&C[(size_t)m * D_MODEL + n0] = v;
        }
    }
}

// ---------------------------------------------------------------------------
// bf16 MFMA causal flash attention, paired q-tiles + double-buffered K/V
// (r7 configuration, unchanged).
// ---------------------------------------------------------------------------
__device__ __forceinline__ void flash_tile(
    int qt, const size_t qbase, const size_t vbase,
    const ushort_t* __restrict__ Qp, const ushort_t* __restrict__ Kp,
    const ushort_t* __restrict__ Vt, ushort_t* __restrict__ Hc,
    ushort_t* Ks0, ushort_t* Ks1, ushort_t* Vs0, ushort_t* Vs1,
    ushort_t (*Ps)[16 * 72])
{
    const int tid  = threadIdx.x;
    const int w    = tid >> 6, lane = tid & 63;
    const int quad = lane >> 4, lx = lane & 15;

    // ensure previous tile's consumers are done before overwriting buf0
    asm volatile("s_barrier" ::: "memory");

    // prologue: stage k-tile 0 into buffer 0
    {
#pragma unroll
        for (int i = 0; i < 2; ++i) {
            int r0 = (w + i * 4) * 8;
            int rl = r0 + (lane >> 3);
            int g  = (lane & 7) ^ (rl & 7);
            gll16(&Kp[qbase + (size_t)rl * D_MODEL + g * 8], &Ks0[r0 * 64]);
            gll16(&Vt[vbase + (size_t)rl * SEQ + g * 8], &Vs0[r0 * 64]);
        }
    }

    // Q fragments (row qt*64 + w*16 + lx), resident across all k-tiles
    short8 qf[2];
    {
        size_t ro = qbase + (size_t)(qt * 64 + w * 16 + lx) * D_MODEL + quad * 8;
        qf[0] = *(const short8*)&Qp[ro];
        qf[1] = *(const short8*)&Qp[ro + 32];
    }

    f32x4 O[4];           // O^T frags: d = nt*16+quad*4+r, q = lx
#pragma unroll
    for (int nt = 0; nt < 4; ++nt) O[nt] = (f32x4){0.f, 0.f, 0.f, 0.f};
    float mrow = -INFINITY, lrow = 0.f;   // per-lane state, q = lx
    const int qin = w * 16 + lx;          // q index within the 64-row tile

    for (int kt = 0; kt <= qt; ++kt) {
        ushort_t* Ks = (kt & 1) ? Ks1 : Ks0;
        ushort_t* Vs = (kt & 1) ? Vs1 : Vs0;

        // tile-kt loads were issued one full iteration ago
        asm volatile("s_waitcnt vmcnt(0)" ::: "memory");
        asm volatile("s_barrier" ::: "memory");

        // prefetch k-tile kt+1 into the other buffer (overlaps compute below)
        if (kt < qt) {
            ushort_t* Kn = (kt & 1) ? Ks0 : Ks1;
            ushort_t* Vn = (kt & 1) ? Vs0 : Vs1;
#pragma unroll
            for (int i = 0; i < 2; ++i) {
                int r0 = (w + i * 4) * 8;
                int rl = r0 + (lane >> 3);
                int g  = (lane & 7) ^ (rl & 7);
                gll16(&Kp[qbase + (size_t)((kt + 1) * 64 + rl) * D_MODEL + g * 8], &Kn[r0 * 64]);
                gll16(&Vt[vbase + (size_t)rl * SEQ + (kt + 1) * 64 + g * 8], &Vn[r0 * 64]);
            }
        }

        // S^T = K Q^T : s[nt][r] = S[q=lx][k = nt*16+quad*4+r]
        f32x4 s[4];
#pragma unroll
        for (int nt = 0; nt < 4; ++nt) {
            int r = nt * 16 + lx;
            short8 kf0 = *(const short8*)&Ks[r * 64 + ((quad ^ (r & 7)) << 3)];
            short8 kf1 = *(const short8*)&Ks[r * 64 + (((4 + quad) ^ (r & 7)) << 3)];
            f32x4 z = (f32x4){0.f, 0.f, 0.f, 0.f};
            z = __builtin_amdgcn_mfma_f32_16x16x32_bf16(kf0, qf[0], z, 0, 0, 0);
            z = __builtin_amdgcn_mfma_f32_16x16x32_bf16(kf1, qf[1], z, 0, 0, 0);
            s[nt] = z;
        }

        // causal mask (diagonal tile only); values already in log2 domain
        if (kt == qt) {
#pragma unroll
            for (int nt = 0; nt < 4; ++nt)
#pragma unroll
                for (int r = 0; r < 4; ++r)
                    if ((nt * 16 + quad * 4 + r) > qin) s[nt][r] = -INFINITY;
        }

        // online softmax: all 16 values are one q-row (q = lx)
        float tm = -INFINITY;
#pragma unroll
        for (int nt = 0; nt < 4; ++nt)
#pragma unroll
            for (int r = 0; r < 4; ++r) tm = fmaxf(tm, s[nt][r]);
        tm = fmaxf(tm, __shfl_xor(tm, 16, 64));
        tm = fmaxf(tm, __shfl_xor(tm, 32, 64));
        float mnew = fmaxf(mrow, tm);
        float alpha = __builtin_amdgcn_exp2f(mrow - mnew);
        mrow = mnew;
        float rs = 0.f;
#pragma unroll
        for (int nt = 0; nt < 4; ++nt)
#pragma unroll
            for (int r = 0; r < 4; ++r) {
                float p = __builtin_amdgcn_exp2f(s[nt][r] - mnew);
                s[nt][r] = p;
                rs += p;
            }
        rs += __shfl_xor(rs, 16, 64);
        rs += __shfl_xor(rs, 32, 64);
        lrow = lrow * alpha + rs;
#pragma unroll
        for (int nt = 0; nt < 4; ++nt)
#pragma unroll
            for (int r = 0; r < 4; ++r) O[nt][r] *= alpha;

        // P -> per-wave LDS, k-consecutive: one b64 per nt
#pragma unroll
        for (int nt = 0; nt < 4; ++nt) {
            uint2 u;
            u.x = pk2(s[nt][0], s[nt][1]);
            u.y = pk2(s[nt][2], s[nt][3]);
            *(uint2*)&Ps[w][lx * 72 + nt * 16 + quad * 4] = u;
        }

        // P A/B-frags (same-wave LDS RAW, in-order per wave)
        short8 pf0 = *(const short8*)&Ps[w][lx * 72 + quad * 8];
        short8 pf1 = *(const short8*)&Ps[w][lx * 72 + 32 + quad * 8];

        // O^T += V^T-frag x P-frag
#pragma unroll
        for (int nt = 0; nt < 4; ++nt) {
            int r = nt * 16 + lx;
            short8 vf0 = *(const short8*)&Vs[r * 64 + ((quad ^ (r & 7)) << 3)];
            short8 vf1 = *(const short8*)&Vs[r * 64 + (((4 + quad) ^ (r & 7)) << 3)];
            O[nt] = __builtin_amdgcn_mfma_f32_16x16x32_bf16(vf0, pf0, O[nt], 0, 0, 0);
            O[nt] = __builtin_amdgcn_mfma_f32_16x16x32_bf16(vf1, pf1, O[nt], 0, 0, 0);
        }
    }

    // epilogue: lane writes row q = lx, 4 consecutive d per nt (b64 stores)
    {
        float invl = 1.f / lrow;
        size_t ro = qbase + (size_t)(qt * 64 + w * 16 + lx) * D_MODEL;
#pragma unroll
        for (int nt = 0; nt < 4; ++nt) {
            uint2 u;
            u.x = pk2(O[nt][0] * invl, O[nt][1] * invl);
            u.y = pk2(O[nt][2] * invl, O[nt][3] * invl);
            *(uint2*)&Hc[ro + nt * 16 + quad * 4] = u;
        }
    }
}

__global__ __launch_bounds__(256) void flash_mfma(
    const ushort_t* __restrict__ Qp, const ushort_t* __restrict__ Kp,
    const ushort_t* __restrict__ Vt, ushort_t* __restrict__ Hc)
{
    const int p  = blockIdx.x;            // pair index 0..NQT/2-1
    const int bh = blockIdx.y;
    const int b = bh >> 4, h = bh & 15;

    __shared__ ushort_t Ks0[64 * 64], Ks1[64 * 64];
    __shared__ ushort_t Vs0[64 * 64], Vs1[64 * 64];
    __shared__ ushort_t Ps[4][16 * 72];   // per-wave P[q][k], stride 72

    const size_t qbase = (size_t)(b * SEQ) * D_MODEL + h * DK;
    const size_t vbase = (size_t)bh * DK * SEQ;

    // big tile first, then its small partner: exactly NQT+1 k-iters per block
    flash_tile(NQT - 1 - p, qbase, vbase, Qp, Kp, Vt, Hc, Ks0, Ks1, Vs0, Vs1, Ps);
    flash_tile(p,           qbase, vbase, Qp, Kp, Vt, Hc, Ks0, Ks1, Vs0, Vs1, Ps);
}

extern "C" void kernel_launch(void* const* d_in, const int* in_sizes, int n_in,
                              void* d_out, int out_size, void* d_ws, size_t ws_size,
                              hipStream_t stream) {
    const float* inQ = (const float*)d_in[0];
    const float* inK = (const float*)d_in[1];
    const float* inV = (const float*)d_in[2];
    const float* Wq  = (const float*)d_in[3];
    const float* bq  = (const float*)d_in[4];
    const float* Wk  = (const float*)d_in[5];
    const float* bk  = (const float*)d_in[6];
    const float* Wv  = (const float*)d_in[7];
    const float* bv  = (const float*)d_in[8];
    const float* Wo  = (const float*)d_in[9];
    const float* bo  = (const float*)d_in[10];
    float* out = (float*)d_out;

    const size_t NI = (size_t)MROWS * D_MODEL;      // 4M
    const size_t NW = (size_t)D_MODEL * D_MODEL;    // 1M
    ushort_t* ws  = (ushort_t*)d_ws;
    ushort_t* Qb  = ws;                // bf16 inputs
    ushort_t* Kb  = Qb  + NI;
    ushort_t* Vb  = Kb  + NI;
    ushort_t* Wqb = Vb  + NI;          // bf16 weights
    ushort_t* Wkb = Wqb + NW;
    ushort_t* Wvb = Wkb + NW;
    ushort_t* Wob = Wvb + NW;
    ushort_t* Qp  = Wob + NW;          // projections
    ushort_t* Kp  = Qp  + NI;
    ushort_t* Vtg = Kp  + NI;          // V^T [B*H][DK][SEQ]
    ushort_t* Hc  = Vtg + NI;

    // fp32 -> bf16 (all 7 tensors, one launch)
    cvt_bf16<<<dim3(NI / 1024, 7), 256, 0, stream>>>(
        inQ, inK, inV, Wq, Wk, Wv, Wo,
        Qb, Kb, Vb, Wqb, Wkb, Wvb, Wob, (int)NI, (int)NW);

    // fused QKV projection; Q pre-scaled by 1/sqrt(dk)*log2(e); V transposed
    const float qsc = 0.125f * 1.44269504088896340736f;
    GemmArgs aq{Qb, Wqb, bq, (void*)Qp, 0, qsc};
    GemmArgs ak{Kb, Wkb, bk, (void*)Kp, 0, 1.0f};
    GemmArgs av{Vb, Wvb, bv, (void*)Vtg, 1, 1.0f};
    gemm_mfma<<<dim3(MROWS / 128, D_MODEL / 128, 3), 256, 0, stream>>>(aq, ak, av);

    // attention (paired q-tiles, dbuf K/V pipeline)
    flash_mfma<<<dim3(NQT / 2, BATCH * NHEADS), 256, 0, stream>>>(Qp, Kp, Vtg, Hc);

    // output projection (fp32 out), 64x128 single-buffer tiles, 512 blocks
    gemm_o<<<dim3(MROWS / 64, D_MODEL / 128), 256, 0, stream>>>(Hc, Wob, bo, out);
}